// Round 1
// baseline (4034.845 us; speedup 1.0000x reference)
//
#include <hip/hip_runtime.h>
#include <math.h>

// ---------------- problem constants ----------------
#define BN_  4
#define TT   24
#define NN   4096
#define TO   12
#define MM   128
#define LL   (TO*MM)          // 1536
#define BL   (BN_*LL)         // 6144
#define DM   512
#define NH   8
#define DH   64
#define MLPD 1024
#define NC   30

// output layout (floats): logits | contrastive | features
#define OUT_LOGITS 0
#define OUT_CONTR  (BN_*NC)                 // 120
#define OUT_FEATS  (OUT_CONTR + BL*DM)      // 120 + 3145728

// exact (non-FMA-contracted) squared distance, matching XLA's mul+add order
__device__ __forceinline__ float d2_3(float ax, float ay, float az,
                                      float bx, float by, float bz) {
#pragma clang fp contract(off)
  float dx = ax - bx, dy = ay - by, dz = az - bz;
  float dx2 = dx * dx, dy2 = dy * dy, dz2 = dz * dz;
  return (dx2 + dy2) + dz2;
}

__device__ __forceinline__ float gelu_f(float v) {
  return 0.5f * v * (1.0f + erff(v * 0.70710678118654752440f));
}

// ---------------- FPS: one block per (b, ti) ----------------
__global__ __launch_bounds__(256) void fps_kernel(const float* __restrict__ xyzs,
                                                  float* __restrict__ anchor) {
  __shared__ float sx[NN], sy[NN], sz[NN];
  __shared__ float swv[4];
  __shared__ int   swi[4];
  __shared__ int   s_next;
  int blk = blockIdx.x;
  int b = blk / TO, ti = blk - b * TO;
  int frame = 2 * ti;  // orig frame = t_idx[ti]-1 = 2*ti
  const float* src = xyzs + ((size_t)(b * TT + frame)) * NN * 3;
  int tid = threadIdx.x;
  float dist[16], px[16], py[16], pz[16];
#pragma unroll
  for (int s = 0; s < 16; ++s) {
    int p = tid + s * 256;
    px[s] = src[p * 3 + 0]; py[s] = src[p * 3 + 1]; pz[s] = src[p * 3 + 2];
    sx[p] = px[s]; sy[p] = py[s]; sz[p] = pz[s];
    dist[s] = 1e10f;
  }
  __syncthreads();
  float lx = sx[0], ly = sy[0], lz = sz[0];
  float* aout = anchor + (size_t)blk * MM * 3;
  if (tid == 0) { aout[0] = lx; aout[1] = ly; aout[2] = lz; }
  for (int j = 1; j < MM; ++j) {
    float bestv = -1.0f; int besti = 0;
#pragma unroll
    for (int s = 0; s < 16; ++s) {
      float d2 = d2_3(px[s], py[s], pz[s], lx, ly, lz);
      float dn = fminf(dist[s], d2);
      dist[s] = dn;
      if (dn > bestv) { bestv = dn; besti = tid + s * 256; }  // ascending idx: strict > keeps first
    }
    for (int m = 1; m < 64; m <<= 1) {
      float ov = __shfl_xor(bestv, m, 64);
      int   oi = __shfl_xor(besti, m, 64);
      if (ov > bestv || (ov == bestv && oi < besti)) { bestv = ov; besti = oi; }
    }
    if ((tid & 63) == 0) { swv[tid >> 6] = bestv; swi[tid >> 6] = besti; }
    __syncthreads();
    if (tid == 0) {
      float bv = swv[0]; int bi = swi[0];
      for (int q = 1; q < 4; ++q)
        if (swv[q] > bv || (swv[q] == bv && swi[q] < bi)) { bv = swv[q]; bi = swi[q]; }
      s_next = bi;
      aout[j * 3 + 0] = sx[bi]; aout[j * 3 + 1] = sy[bi]; aout[j * 3 + 2] = sz[bi];
    }
    __syncthreads();
    int nxt = s_next;
    lx = sx[nxt]; ly = sy[nxt]; lz = sz[nxt];
  }
}

// ---------------- ball query + p4dconv + max-pool: one wave per (b,ti,m) ----------------
__global__ __launch_bounds__(64) void ballconv_kernel(
    const float* __restrict__ xyzs, const float* __restrict__ oldf,
    const float* __restrict__ anchor,
    const float* __restrict__ wdw, const float* __restrict__ wfw,
    float* __restrict__ dout) {
  __shared__ int   sidx[32];
  __shared__ float sdisp[32][4];
  __shared__ float sfeat[32][2];
  int blk = blockIdx.x;               // = b*LL + ti*MM + mm
  int b = blk / (TO * MM);
  int rem = blk - b * (TO * MM);
  int ti = rem / MM;
  int lane = threadIdx.x;
  const float* ap = anchor + (size_t)blk * 3;
  float ax = ap[0], ay = ap[1], az = ap[2];
  int d0 = lane * 8;
  float4 wd[8]; float2 wf[8];
#pragma unroll
  for (int jd = 0; jd < 8; ++jd) {
    wd[jd] = *(const float4*)(wdw + (d0 + jd) * 4);
    wf[jd] = *(const float2*)(wfw + (d0 + jd) * 2);
  }
  float fmx[8];
#pragma unroll
  for (int jd = 0; jd < 8; ++jd) fmx[jd] = -INFINITY;

  for (int o = -1; o <= 1; ++o) {
    int tp = 1 + 2 * ti + o;
    int orig = (tp == 0) ? 0 : tp - 1;
    const float* nx = xyzs + ((size_t)(b * TT + orig)) * NN * 3;
    const float* nf = oldf + ((size_t)(b * TT + orig)) * 2 * NN;
    int cnt = 0;
    for (int base = 0; base < NN && cnt < 32; base += 64) {
      int p = base + lane;
      float d2 = d2_3(ax, ay, az, nx[p * 3], nx[p * 3 + 1], nx[p * 3 + 2]);
      bool in = d2 < 0.09f;  // (float)(0.3*0.3)
      unsigned long long mask = __ballot(in);
      int pos = __popcll(mask & ((1ull << lane) - 1ull));
      if (in && (cnt + pos) < 32) sidx[cnt + pos] = p;
      cnt += __popcll(mask);
    }
    __syncthreads();
    int used = cnt < 32 ? cnt : 32;
    if (lane < 32 && lane >= used) sidx[lane] = (used > 0) ? sidx[0] : 0;
    __syncthreads();
    if (lane < 32) {
      int p = sidx[lane];
      sdisp[lane][0] = nx[p * 3 + 0] - ax;
      sdisp[lane][1] = nx[p * 3 + 1] - ay;
      sdisp[lane][2] = nx[p * 3 + 2] - az;
      sdisp[lane][3] = (float)o;
      sfeat[lane][0] = nf[p];
      sfeat[lane][1] = nf[NN + p];
    }
    __syncthreads();
    for (int k = 0; k < 32; ++k) {
      float p0 = sdisp[k][0], p1 = sdisp[k][1], p2 = sdisp[k][2], p3 = sdisp[k][3];
      float f0 = sfeat[k][0], f1 = sfeat[k][1];
#pragma unroll
      for (int jd = 0; jd < 8; ++jd) {
        float de = wd[jd].x * p0 + wd[jd].y * p1 + wd[jd].z * p2 + wd[jd].w * p3;
        float fe = wf[jd].x * f0 + wf[jd].y * f1;
        fmx[jd] = fmaxf(fmx[jd], fe * de);
      }
    }
    __syncthreads();
  }
  float* fout = dout + OUT_FEATS + (size_t)blk * DM + d0;
#pragma unroll
  for (int jd = 0; jd < 8; jd += 4)
    *(float4*)(fout + jd) = make_float4(fmx[jd], fmx[jd + 1], fmx[jd + 2], fmx[jd + 3]);
}

// ---------------- pos/contrastive embed + x = relu(pos + features) ----------------
__global__ __launch_bounds__(256) void posx_kernel(
    const float* __restrict__ anchor,
    const float* __restrict__ pw, const float* __restrict__ pb,
    const float* __restrict__ cw, const float* __restrict__ cb,
    float* __restrict__ dout, float* __restrict__ x) {
  int idx = blockIdx.x * 256 + threadIdx.x;  // < BL*DM
  int bl = idx >> 9, d = idx & 511;
  int ti = (bl % LL) / MM;
  const float* ap = anchor + (size_t)bl * 3;
  float c0 = ap[0], c1 = ap[1], c2 = ap[2], c3 = (float)(ti + 1);
  float4 pwv = *(const float4*)(pw + d * 4);
  float4 cwv = *(const float4*)(cw + d * 4);
  float pos = pwv.x * c0 + pwv.y * c1 + pwv.z * c2 + pwv.w * c3 + pb[d];
  float con = cwv.x * c0 + cwv.y * c1 + cwv.z * c2 + cwv.w * c3 + cb[d];
  dout[OUT_CONTR + (size_t)idx] = con;
  float v = pos + dout[OUT_FEATS + (size_t)idx];
  x[idx] = v > 0.0f ? v : 0.0f;
}

// ---------------- LayerNorm: one wave per row of 512 ----------------
__global__ __launch_bounds__(64) void ln_kernel(
    const float* __restrict__ x, const float* __restrict__ gs,
    const float* __restrict__ gb, float* __restrict__ out) {
  int row = blockIdx.x, lane = threadIdx.x;
  const float* xr = x + (size_t)row * DM + lane * 8;
  float4 v0 = *(const float4*)xr;
  float4 v1 = *(const float4*)(xr + 4);
  float v[8] = {v0.x, v0.y, v0.z, v0.w, v1.x, v1.y, v1.z, v1.w};
  float s = 0.f;
#pragma unroll
  for (int j = 0; j < 8; ++j) s += v[j];
  for (int m = 1; m < 64; m <<= 1) s += __shfl_xor(s, m, 64);
  float mu = s * (1.0f / DM);
  float d[8], ss = 0.f;
#pragma unroll
  for (int j = 0; j < 8; ++j) { d[j] = v[j] - mu; ss += d[j] * d[j]; }
  for (int m = 1; m < 64; m <<= 1) ss += __shfl_xor(ss, m, 64);
  float rs = 1.0f / sqrtf(ss * (1.0f / DM) + 1e-5f);
  const float* gsr = gs + lane * 8;
  const float* gbr = gb + lane * 8;
  float* orow = out + (size_t)row * DM + lane * 8;
  float r[8];
#pragma unroll
  for (int j = 0; j < 8; ++j) r[j] = d[j] * rs * gsr[j] + gbr[j];
  *(float4*)orow       = make_float4(r[0], r[1], r[2], r[3]);
  *(float4*)(orow + 4) = make_float4(r[4], r[5], r[6], r[7]);
}

// ---------------- tiled fp32 GEMM: C = A(MxK) * W(NxK)^T (+bias)(+gelu)(+res) ----------------
// EPI: 0 = none, 2 = bias+gelu, 3 = bias+residual
template <int EPI>
__global__ __launch_bounds__(256) void gemm_kernel(
    const float* __restrict__ A, const float* __restrict__ W,
    const float* __restrict__ bias, const float* __restrict__ res,
    float* __restrict__ C, int M, int N, int K) {
  __shared__ __align__(16) float As[16 * 68];
  __shared__ __align__(16) float Bs[16 * 68];
  int tid = threadIdx.x, ty = tid >> 4, tx = tid & 15;
  int row0 = blockIdx.y * 64, col0 = blockIdx.x * 64;
  int lr = tid >> 2, lk = (tid & 3) * 4;
  const float* Ap = A + (size_t)(row0 + lr) * K + lk;
  const float* Wp = W + (size_t)(col0 + lr) * K + lk;
  float acc[4][4] = {};
  for (int kk = 0; kk < K; kk += 16) {
    float4 a4 = *(const float4*)(Ap + kk);
    float4 w4 = *(const float4*)(Wp + kk);
    __syncthreads();
    As[(lk + 0) * 68 + lr] = a4.x; As[(lk + 1) * 68 + lr] = a4.y;
    As[(lk + 2) * 68 + lr] = a4.z; As[(lk + 3) * 68 + lr] = a4.w;
    Bs[(lk + 0) * 68 + lr] = w4.x; Bs[(lk + 1) * 68 + lr] = w4.y;
    Bs[(lk + 2) * 68 + lr] = w4.z; Bs[(lk + 3) * 68 + lr] = w4.w;
    __syncthreads();
#pragma unroll
    for (int k = 0; k < 16; ++k) {
      const float4 av = *(const float4*)&As[k * 68 + ty * 4];
      const float4 bv = *(const float4*)&Bs[k * 68 + tx * 4];
      acc[0][0] += av.x * bv.x; acc[0][1] += av.x * bv.y; acc[0][2] += av.x * bv.z; acc[0][3] += av.x * bv.w;
      acc[1][0] += av.y * bv.x; acc[1][1] += av.y * bv.y; acc[1][2] += av.y * bv.z; acc[1][3] += av.y * bv.w;
      acc[2][0] += av.z * bv.x; acc[2][1] += av.z * bv.y; acc[2][2] += av.z * bv.z; acc[2][3] += av.z * bv.w;
      acc[3][0] += av.w * bv.x; acc[3][1] += av.w * bv.y; acc[3][2] += av.w * bv.z; acc[3][3] += av.w * bv.w;
    }
  }
#pragma unroll
  for (int ii = 0; ii < 4; ++ii) {
    int r = row0 + ty * 4 + ii;
    size_t off = (size_t)r * N + col0 + tx * 4;
    float4 v = make_float4(acc[ii][0], acc[ii][1], acc[ii][2], acc[ii][3]);
    if (EPI != 0) {
      float4 bb = *(const float4*)(bias + col0 + tx * 4);
      v.x += bb.x; v.y += bb.y; v.z += bb.z; v.w += bb.w;
    }
    if (EPI == 2) { v.x = gelu_f(v.x); v.y = gelu_f(v.y); v.z = gelu_f(v.z); v.w = gelu_f(v.w); }
    if (EPI == 3) {
      float4 rr = *(const float4*)(res + off);
      v.x += rr.x; v.y += rr.y; v.z += rr.z; v.w += rr.w;
    }
    *(float4*)(C + off) = v;
  }
}

// ---------------- flash attention fp32: block = (i-tile 64 rows) x (b,h) ----------------
#define AST 68
#define DOT4(qa, kb) (qa.x * kb.x + qa.y * kb.y + qa.z * kb.z + qa.w * kb.w)
__global__ __launch_bounds__(256) void attn_kernel(const float* __restrict__ qkv,
                                                   float* __restrict__ outp) {
  __shared__ __align__(16) float Qs[64 * AST];
  __shared__ __align__(16) float KPs[64 * AST];  // holds K tile, then reused for P
  __shared__ __align__(16) float Vs[64 * 64];
  int it = blockIdx.x, bh = blockIdx.y;
  int b = bh >> 3, h = bh & 7;
  int tid = threadIdx.x, ty = tid >> 4, tx = tid & 15;
  int i0 = it * 64;
  size_t rowbase = (size_t)b * LL;
  {
    int r = tid >> 2, c0 = (tid & 3) * 16;
    const float* src = qkv + (rowbase + i0 + r) * (3 * DM) + h * DH + c0;
#pragma unroll
    for (int j = 0; j < 4; ++j)
      *(float4*)&Qs[r * AST + c0 + 4 * j] = *(const float4*)(src + 4 * j);
  }
  float m_i[4], l_i[4], acc[4][4];
#pragma unroll
  for (int ii = 0; ii < 4; ++ii) {
    m_i[ii] = -INFINITY; l_i[ii] = 0.f;
#pragma unroll
    for (int jj = 0; jj < 4; ++jj) acc[ii][jj] = 0.f;
  }
  for (int jt = 0; jt < LL / 64; ++jt) {
    __syncthreads();
    {
      int r = tid >> 2, c0 = (tid & 3) * 16;
      const float* ksrc = qkv + (rowbase + jt * 64 + r) * (3 * DM) + DM + h * DH + c0;
      const float* vsrc = ksrc + DM;
#pragma unroll
      for (int j = 0; j < 4; ++j) {
        *(float4*)&KPs[r * AST + c0 + 4 * j] = *(const float4*)(ksrc + 4 * j);
        *(float4*)&Vs[r * 64 + c0 + 4 * j]  = *(const float4*)(vsrc + 4 * j);
      }
    }
    __syncthreads();
    float s[4][4] = {};
    for (int dd = 0; dd < 64; dd += 4) {
      float4 q0 = *(const float4*)&Qs[(ty * 4 + 0) * AST + dd];
      float4 q1 = *(const float4*)&Qs[(ty * 4 + 1) * AST + dd];
      float4 q2 = *(const float4*)&Qs[(ty * 4 + 2) * AST + dd];
      float4 q3 = *(const float4*)&Qs[(ty * 4 + 3) * AST + dd];
      float4 k0 = *(const float4*)&KPs[(tx * 4 + 0) * AST + dd];
      float4 k1 = *(const float4*)&KPs[(tx * 4 + 1) * AST + dd];
      float4 k2 = *(const float4*)&KPs[(tx * 4 + 2) * AST + dd];
      float4 k3 = *(const float4*)&KPs[(tx * 4 + 3) * AST + dd];
      s[0][0] += DOT4(q0, k0); s[0][1] += DOT4(q0, k1); s[0][2] += DOT4(q0, k2); s[0][3] += DOT4(q0, k3);
      s[1][0] += DOT4(q1, k0); s[1][1] += DOT4(q1, k1); s[1][2] += DOT4(q1, k2); s[1][3] += DOT4(q1, k3);
      s[2][0] += DOT4(q2, k0); s[2][1] += DOT4(q2, k1); s[2][2] += DOT4(q2, k2); s[2][3] += DOT4(q2, k3);
      s[3][0] += DOT4(q3, k0); s[3][1] += DOT4(q3, k1); s[3][2] += DOT4(q3, k2); s[3][3] += DOT4(q3, k3);
    }
    float pr[4][4];
#pragma unroll
    for (int ii = 0; ii < 4; ++ii) {
      float mr = -INFINITY;
#pragma unroll
      for (int jj = 0; jj < 4; ++jj) { s[ii][jj] *= 0.125f; mr = fmaxf(mr, s[ii][jj]); }
      for (int m = 1; m < 16; m <<= 1) mr = fmaxf(mr, __shfl_xor(mr, m, 64));
      float mn = fmaxf(m_i[ii], mr);
      float alpha = expf(m_i[ii] - mn);
      float ps = 0.f;
#pragma unroll
      for (int jj = 0; jj < 4; ++jj) { float p = expf(s[ii][jj] - mn); pr[ii][jj] = p; ps += p; }
      for (int m = 1; m < 16; m <<= 1) ps += __shfl_xor(ps, m, 64);
      l_i[ii] = l_i[ii] * alpha + ps;
      m_i[ii] = mn;
#pragma unroll
      for (int jj = 0; jj < 4; ++jj) acc[ii][jj] *= alpha;
    }
    __syncthreads();  // all K reads done, safe to overwrite with P
#pragma unroll
    for (int ii = 0; ii < 4; ++ii)
      *(float4*)&KPs[(ty * 4 + ii) * AST + tx * 4] =
          make_float4(pr[ii][0], pr[ii][1], pr[ii][2], pr[ii][3]);
    __syncthreads();
    for (int kk = 0; kk < 64; kk += 4) {
      float4 p0 = *(const float4*)&KPs[(ty * 4 + 0) * AST + kk];
      float4 p1 = *(const float4*)&KPs[(ty * 4 + 1) * AST + kk];
      float4 p2 = *(const float4*)&KPs[(ty * 4 + 2) * AST + kk];
      float4 p3 = *(const float4*)&KPs[(ty * 4 + 3) * AST + kk];
      float4 w0 = *(const float4*)&Vs[(kk + 0) * 64 + tx * 4];
      float4 w1 = *(const float4*)&Vs[(kk + 1) * 64 + tx * 4];
      float4 w2 = *(const float4*)&Vs[(kk + 2) * 64 + tx * 4];
      float4 w3 = *(const float4*)&Vs[(kk + 3) * 64 + tx * 4];
#define PVROW(ii, pp)                                                     \
      acc[ii][0] += pp.x * w0.x + pp.y * w1.x + pp.z * w2.x + pp.w * w3.x; \
      acc[ii][1] += pp.x * w0.y + pp.y * w1.y + pp.z * w2.y + pp.w * w3.y; \
      acc[ii][2] += pp.x * w0.z + pp.y * w1.z + pp.z * w2.z + pp.w * w3.z; \
      acc[ii][3] += pp.x * w0.w + pp.y * w1.w + pp.z * w2.w + pp.w * w3.w;
      PVROW(0, p0) PVROW(1, p1) PVROW(2, p2) PVROW(3, p3)
#undef PVROW
    }
  }
#pragma unroll
  for (int ii = 0; ii < 4; ++ii) {
    float inv = 1.0f / l_i[ii];
    *(float4*)(outp + (rowbase + i0 + ty * 4 + ii) * DM + h * DH + tx * 4) =
        make_float4(acc[ii][0] * inv, acc[ii][1] * inv, acc[ii][2] * inv, acc[ii][3] * inv);
  }
}

// ---------------- max-pool over sequence ----------------
__global__ __launch_bounds__(256) void poolmax_kernel(const float* __restrict__ x,
                                                      float* __restrict__ pooled) {
  int idx = blockIdx.x * 256 + threadIdx.x;  // < BN_*DM
  int b = idx >> 9, d = idx & 511;
  float m = -INFINITY;
  const float* p = x + (size_t)b * LL * DM + d;
  for (int l = 0; l < LL; ++l) m = fmaxf(m, p[(size_t)l * DM]);
  pooled[idx] = m;
}

// ---------------- head MLP ----------------
__global__ __launch_bounds__(256) void head1_kernel(const float* __restrict__ lnp,
                                                    const float* __restrict__ w,
                                                    const float* __restrict__ bb,
                                                    float* __restrict__ hid) {
  int idx = blockIdx.x * 256 + threadIdx.x;  // < BN_*MLPD
  int b = idx >> 10, n = idx & 1023;
  const float* xr = lnp + (size_t)b * DM;
  const float* wr = w + (size_t)n * DM;
  float s = 0.f;
  for (int k = 0; k < DM; k += 4) {
    float4 xv = *(const float4*)(xr + k);
    float4 wv = *(const float4*)(wr + k);
    s += xv.x * wv.x + xv.y * wv.y + xv.z * wv.z + xv.w * wv.w;
  }
  hid[idx] = gelu_f(s + bb[n]);
}

__global__ __launch_bounds__(128) void head2_kernel(const float* __restrict__ hid,
                                                    const float* __restrict__ w,
                                                    const float* __restrict__ bb,
                                                    float* __restrict__ dout) {
  int t = threadIdx.x;
  if (t < BN_ * NC) {
    int b = t / NC, n = t - b * NC;
    const float* xr = hid + (size_t)b * MLPD;
    const float* wr = w + (size_t)n * MLPD;
    float s = 0.f;
    for (int k = 0; k < MLPD; k += 4) {
      float4 xv = *(const float4*)(xr + k);
      float4 wv = *(const float4*)(wr + k);
      s += xv.x * wv.x + xv.y * wv.y + xv.z * wv.z + xv.w * wv.w;
    }
    dout[OUT_LOGITS + t] = s + bb[n];
  }
}

// ---------------- launch ----------------
extern "C" void kernel_launch(void* const* d_in, const int* in_sizes, int n_in,
                              void* d_out, int out_size, void* d_ws, size_t ws_size,
                              hipStream_t stream) {
  (void)in_sizes; (void)n_in; (void)out_size; (void)ws_size;
  const float* xyzs     = (const float*)d_in[0];
  const float* oldf     = (const float*)d_in[1];
  const float* conv_d_w = (const float*)d_in[2];
  const float* conv_f_w = (const float*)d_in[3];
  const float* pos_w    = (const float*)d_in[4];
  const float* pos_b    = (const float*)d_in[5];
  const float* contr_w  = (const float*)d_in[6];
  const float* contr_b  = (const float*)d_in[7];
  const float* ln1_s    = (const float*)d_in[8];
  const float* ln1_b    = (const float*)d_in[9];
  const float* qkv_w    = (const float*)d_in[10];
  const float* out_w    = (const float*)d_in[11];
  const float* out_b    = (const float*)d_in[12];
  const float* ln2_s    = (const float*)d_in[13];
  const float* ln2_b    = (const float*)d_in[14];
  const float* ff1_w    = (const float*)d_in[15];
  const float* ff1_b    = (const float*)d_in[16];
  const float* ff2_w    = (const float*)d_in[17];
  const float* ff2_b    = (const float*)d_in[18];
  const float* hl_s     = (const float*)d_in[19];
  const float* hl_b     = (const float*)d_in[20];
  const float* h1_w     = (const float*)d_in[21];
  const float* h1_b     = (const float*)d_in[22];
  const float* h2_w     = (const float*)d_in[23];
  const float* h2_b     = (const float*)d_in[24];
  float* dout = (float*)d_out;
  float* ws = (float*)d_ws;

  size_t off = 0;
  float* anchor = ws + off; off += (size_t)BN_ * TO * MM * 3;
  off = (off + 63) & ~(size_t)63;
  float* x     = ws + off; off += (size_t)BL * DM;
  float* hbuf  = ws + off; off += (size_t)BL * DM;
  float* qkvb  = ws + off; off += (size_t)BL * 3 * DM;
  float* attno = ws + off; off += (size_t)BL * DM;
  float* pooled = ws + off; off += BN_ * DM;
  float* lnp    = ws + off; off += BN_ * DM;
  float* hid    = ws + off; off += BN_ * MLPD;
  float* ffb = qkvb;  // reuse qkv buffer for FF hidden

  fps_kernel<<<BN_ * TO, 256, 0, stream>>>(xyzs, anchor);
  ballconv_kernel<<<BN_ * TO * MM, 64, 0, stream>>>(xyzs, oldf, anchor, conv_d_w, conv_f_w, dout);
  posx_kernel<<<(BL * DM) / 256, 256, 0, stream>>>(anchor, pos_w, pos_b, contr_w, contr_b, dout, x);

  for (int l = 0; l < 4; ++l) {
    ln_kernel<<<BL, 64, 0, stream>>>(x, ln1_s + l * DM, ln1_b + l * DM, hbuf);
    gemm_kernel<0><<<dim3(3 * DM / 64, BL / 64), 256, 0, stream>>>(
        hbuf, qkv_w + (size_t)l * 3 * DM * DM, nullptr, nullptr, qkvb, BL, 3 * DM, DM);
    attn_kernel<<<dim3(LL / 64, BN_ * NH), 256, 0, stream>>>(qkvb, attno);
    gemm_kernel<3><<<dim3(DM / 64, BL / 64), 256, 0, stream>>>(
        attno, out_w + (size_t)l * DM * DM, out_b + l * DM, x, x, BL, DM, DM);
    ln_kernel<<<BL, 64, 0, stream>>>(x, ln2_s + l * DM, ln2_b + l * DM, hbuf);
    gemm_kernel<2><<<dim3(MLPD / 64, BL / 64), 256, 0, stream>>>(
        hbuf, ff1_w + (size_t)l * MLPD * DM, ff1_b + l * MLPD, nullptr, ffb, BL, MLPD, DM);
    gemm_kernel<3><<<dim3(DM / 64, BL / 64), 256, 0, stream>>>(
        ffb, ff2_w + (size_t)l * DM * MLPD, ff2_b + l * DM, x, x, BL, DM, MLPD);
  }

  poolmax_kernel<<<(BN_ * DM) / 256, 256, 0, stream>>>(x, pooled);
  ln_kernel<<<BN_, 64, 0, stream>>>(pooled, hl_s, hl_b, lnp);
  head1_kernel<<<(BN_ * MLPD) / 256, 256, 0, stream>>>(lnp, h1_w, h1_b, hid);
  head2_kernel<<<1, 128, 0, stream>>>(hid, h2_w, h2_b, dout);
}

// Round 2
// 3730.042 us; speedup vs baseline: 1.0817x; 1.0817x over previous
//
#include <hip/hip_runtime.h>
#include <math.h>

// ---------------- problem constants ----------------
#define BN_  4
#define TT   24
#define NN   4096
#define TO   12
#define MM   128
#define LL   (TO*MM)          // 1536
#define BL   (BN_*LL)         // 6144
#define DM   512
#define NH   8
#define DH   64
#define MLPD 1024
#define NC   30

// output layout (floats): logits | contrastive | features
#define OUT_LOGITS 0
#define OUT_CONTR  (BN_*NC)                 // 120
#define OUT_FEATS  (OUT_CONTR + BL*DM)      // 120 + 3145728

// exact (non-FMA-contracted) squared distance, matching XLA's mul+add order
__device__ __forceinline__ float d2_3(float ax, float ay, float az,
                                      float bx, float by, float bz) {
#pragma clang fp contract(off)
  float dx = ax - bx, dy = ay - by, dz = az - bz;
  float dx2 = dx * dx, dy2 = dy * dy, dz2 = dz * dz;
  return (dx2 + dy2) + dz2;
}

__device__ __forceinline__ float gelu_f(float v) {
  return 0.5f * v * (1.0f + erff(v * 0.70710678118654752440f));
}

// ---------------- FPS: one block per (b, ti) ----------------
__global__ __launch_bounds__(256) void fps_kernel(const float* __restrict__ xyzs,
                                                  float* __restrict__ anchor) {
  __shared__ float sx[NN], sy[NN], sz[NN];
  __shared__ float swv[4];
  __shared__ int   swi[4];
  __shared__ int   s_next;
  int blk = blockIdx.x;
  int b = blk / TO, ti = blk - b * TO;
  int frame = 2 * ti;  // orig frame = t_idx[ti]-1 = 2*ti
  const float* src = xyzs + ((size_t)(b * TT + frame)) * NN * 3;
  int tid = threadIdx.x;
  float dist[16], px[16], py[16], pz[16];
#pragma unroll
  for (int s = 0; s < 16; ++s) {
    int p = tid + s * 256;
    px[s] = src[p * 3 + 0]; py[s] = src[p * 3 + 1]; pz[s] = src[p * 3 + 2];
    sx[p] = px[s]; sy[p] = py[s]; sz[p] = pz[s];
    dist[s] = 1e10f;
  }
  __syncthreads();
  float lx = sx[0], ly = sy[0], lz = sz[0];
  float* aout = anchor + (size_t)blk * MM * 3;
  if (tid == 0) { aout[0] = lx; aout[1] = ly; aout[2] = lz; }
  for (int j = 1; j < MM; ++j) {
    float bestv = -1.0f; int besti = 0;
#pragma unroll
    for (int s = 0; s < 16; ++s) {
      float d2 = d2_3(px[s], py[s], pz[s], lx, ly, lz);
      float dn = fminf(dist[s], d2);
      dist[s] = dn;
      if (dn > bestv) { bestv = dn; besti = tid + s * 256; }  // ascending idx: strict > keeps first
    }
    for (int m = 1; m < 64; m <<= 1) {
      float ov = __shfl_xor(bestv, m, 64);
      int   oi = __shfl_xor(besti, m, 64);
      if (ov > bestv || (ov == bestv && oi < besti)) { bestv = ov; besti = oi; }
    }
    if ((tid & 63) == 0) { swv[tid >> 6] = bestv; swi[tid >> 6] = besti; }
    __syncthreads();
    if (tid == 0) {
      float bv = swv[0]; int bi = swi[0];
      for (int q = 1; q < 4; ++q)
        if (swv[q] > bv || (swv[q] == bv && swi[q] < bi)) { bv = swv[q]; bi = swi[q]; }
      s_next = bi;
      aout[j * 3 + 0] = sx[bi]; aout[j * 3 + 1] = sy[bi]; aout[j * 3 + 2] = sz[bi];
    }
    __syncthreads();
    int nxt = s_next;
    lx = sx[nxt]; ly = sy[nxt]; lz = sz[nxt];
  }
}

// ---------------- ball query + p4dconv + max-pool: one wave per (b,ti,m) ----------------
__global__ __launch_bounds__(64) void ballconv_kernel(
    const float* __restrict__ xyzs, const float* __restrict__ oldf,
    const float* __restrict__ anchor,
    const float* __restrict__ wdw, const float* __restrict__ wfw,
    float* __restrict__ dout) {
  __shared__ int   sidx[32];
  __shared__ float sdisp[32][4];
  __shared__ float sfeat[32][2];
  int blk = blockIdx.x;               // = b*LL + ti*MM + mm
  int b = blk / (TO * MM);
  int rem = blk - b * (TO * MM);
  int ti = rem / MM;
  int lane = threadIdx.x;
  const float* ap = anchor + (size_t)blk * 3;
  float ax = ap[0], ay = ap[1], az = ap[2];
  int d0 = lane * 8;
  float4 wd[8]; float2 wf[8];
#pragma unroll
  for (int jd = 0; jd < 8; ++jd) {
    wd[jd] = *(const float4*)(wdw + (d0 + jd) * 4);
    wf[jd] = *(const float2*)(wfw + (d0 + jd) * 2);
  }
  float fmx[8];
#pragma unroll
  for (int jd = 0; jd < 8; ++jd) fmx[jd] = -INFINITY;

  for (int o = -1; o <= 1; ++o) {
    int tp = 1 + 2 * ti + o;
    int orig = (tp == 0) ? 0 : tp - 1;
    const float* nx = xyzs + ((size_t)(b * TT + orig)) * NN * 3;
    const float* nf = oldf + ((size_t)(b * TT + orig)) * 2 * NN;
    int cnt = 0;
    for (int base = 0; base < NN && cnt < 32; base += 64) {
      int p = base + lane;
      float d2 = d2_3(ax, ay, az, nx[p * 3], nx[p * 3 + 1], nx[p * 3 + 2]);
      bool in = d2 < 0.09f;  // (float)(0.3*0.3)
      unsigned long long mask = __ballot(in);
      int pos = __popcll(mask & ((1ull << lane) - 1ull));
      if (in && (cnt + pos) < 32) sidx[cnt + pos] = p;
      cnt += __popcll(mask);
    }
    __syncthreads();
    int used = cnt < 32 ? cnt : 32;
    if (lane < 32 && lane >= used) sidx[lane] = (used > 0) ? sidx[0] : 0;
    __syncthreads();
    if (lane < 32) {
      int p = sidx[lane];
      sdisp[lane][0] = nx[p * 3 + 0] - ax;
      sdisp[lane][1] = nx[p * 3 + 1] - ay;
      sdisp[lane][2] = nx[p * 3 + 2] - az;
      sdisp[lane][3] = (float)o;
      sfeat[lane][0] = nf[p];
      sfeat[lane][1] = nf[NN + p];
    }
    __syncthreads();
    for (int k = 0; k < 32; ++k) {
      float p0 = sdisp[k][0], p1 = sdisp[k][1], p2 = sdisp[k][2], p3 = sdisp[k][3];
      float f0 = sfeat[k][0], f1 = sfeat[k][1];
#pragma unroll
      for (int jd = 0; jd < 8; ++jd) {
        float de = wd[jd].x * p0 + wd[jd].y * p1 + wd[jd].z * p2 + wd[jd].w * p3;
        float fe = wf[jd].x * f0 + wf[jd].y * f1;
        fmx[jd] = fmaxf(fmx[jd], fe * de);
      }
    }
    __syncthreads();
  }
  float* fout = dout + OUT_FEATS + (size_t)blk * DM + d0;
#pragma unroll
  for (int jd = 0; jd < 8; jd += 4)
    *(float4*)(fout + jd) = make_float4(fmx[jd], fmx[jd + 1], fmx[jd + 2], fmx[jd + 3]);
}

// ---------------- pos/contrastive embed + x = relu(pos + features) ----------------
__global__ __launch_bounds__(256) void posx_kernel(
    const float* __restrict__ anchor,
    const float* __restrict__ pw, const float* __restrict__ pb,
    const float* __restrict__ cw, const float* __restrict__ cb,
    float* __restrict__ dout, float* __restrict__ x) {
  int idx = blockIdx.x * 256 + threadIdx.x;  // < BL*DM
  int bl = idx >> 9, d = idx & 511;
  int ti = (bl % LL) / MM;
  const float* ap = anchor + (size_t)bl * 3;
  float c0 = ap[0], c1 = ap[1], c2 = ap[2], c3 = (float)(ti + 1);
  float4 pwv = *(const float4*)(pw + d * 4);
  float4 cwv = *(const float4*)(cw + d * 4);
  float pos = pwv.x * c0 + pwv.y * c1 + pwv.z * c2 + pwv.w * c3 + pb[d];
  float con = cwv.x * c0 + cwv.y * c1 + cwv.z * c2 + cwv.w * c3 + cb[d];
  dout[OUT_CONTR + (size_t)idx] = con;
  float v = pos + dout[OUT_FEATS + (size_t)idx];
  x[idx] = v > 0.0f ? v : 0.0f;
}

// ---------------- LayerNorm: one wave per row of 512 ----------------
__global__ __launch_bounds__(64) void ln_kernel(
    const float* __restrict__ x, const float* __restrict__ gs,
    const float* __restrict__ gb, float* __restrict__ out) {
  int row = blockIdx.x, lane = threadIdx.x;
  const float* xr = x + (size_t)row * DM + lane * 8;
  float4 v0 = *(const float4*)xr;
  float4 v1 = *(const float4*)(xr + 4);
  float v[8] = {v0.x, v0.y, v0.z, v0.w, v1.x, v1.y, v1.z, v1.w};
  float s = 0.f;
#pragma unroll
  for (int j = 0; j < 8; ++j) s += v[j];
  for (int m = 1; m < 64; m <<= 1) s += __shfl_xor(s, m, 64);
  float mu = s * (1.0f / DM);
  float d[8], ss = 0.f;
#pragma unroll
  for (int j = 0; j < 8; ++j) { d[j] = v[j] - mu; ss += d[j] * d[j]; }
  for (int m = 1; m < 64; m <<= 1) ss += __shfl_xor(ss, m, 64);
  float rs = 1.0f / sqrtf(ss * (1.0f / DM) + 1e-5f);
  const float* gsr = gs + lane * 8;
  const float* gbr = gb + lane * 8;
  float* orow = out + (size_t)row * DM + lane * 8;
  float r[8];
#pragma unroll
  for (int j = 0; j < 8; ++j) r[j] = d[j] * rs * gsr[j] + gbr[j];
  *(float4*)orow       = make_float4(r[0], r[1], r[2], r[3]);
  *(float4*)(orow + 4) = make_float4(r[4], r[5], r[6], r[7]);
}

// ---------------- tiled fp32 GEMM 128x128: C = A(MxK) * W(NxK)^T (+bias)(+gelu)(+res) ----------------
// EPI: 0 = none, 2 = bias+gelu, 3 = bias+residual
// 256 threads, each owns a 2x2 grid of 4x4 sub-tiles (rows ry*4+i / +64, cols cx*4+j / +64).
#define OP4(accq, av, bv)                                                                   \
  accq[0][0] += av.x * bv.x; accq[0][1] += av.x * bv.y; accq[0][2] += av.x * bv.z; accq[0][3] += av.x * bv.w; \
  accq[1][0] += av.y * bv.x; accq[1][1] += av.y * bv.y; accq[1][2] += av.y * bv.z; accq[1][3] += av.y * bv.w; \
  accq[2][0] += av.z * bv.x; accq[2][1] += av.z * bv.y; accq[2][2] += av.z * bv.z; accq[2][3] += av.z * bv.w; \
  accq[3][0] += av.w * bv.x; accq[3][1] += av.w * bv.y; accq[3][2] += av.w * bv.z; accq[3][3] += av.w * bv.w;

template <int EPI>
__global__ __launch_bounds__(256) void gemm_kernel(
    const float* __restrict__ A, const float* __restrict__ W,
    const float* __restrict__ bias, const float* __restrict__ res,
    float* __restrict__ C, int M, int N, int K) {
  __shared__ float Ast[16 * 128];   // k-major: Ast[k][row]
  __shared__ float Bst[16 * 128];   // k-major: Bst[k][col]
  int tid = threadIdx.x;
  int ry = tid >> 4, cx = tid & 15;
  int row0 = blockIdx.y * 128, col0 = blockIdx.x * 128;
  int lr = tid >> 1;             // 0..127
  int lk = (tid & 1) * 8;        // 0 or 8
  const float* Ap = A + (size_t)(row0 + lr) * K + lk;
  const float* Wp = W + (size_t)(col0 + lr) * K + lk;
  float a00[4][4] = {}, a01[4][4] = {}, a10[4][4] = {}, a11[4][4] = {};
  for (int kk = 0; kk < K; kk += 16) {
    float4 a0 = *(const float4*)(Ap + kk);
    float4 a1 = *(const float4*)(Ap + kk + 4);
    float4 b0 = *(const float4*)(Wp + kk);
    float4 b1 = *(const float4*)(Wp + kk + 4);
    __syncthreads();
    Ast[(lk + 0) * 128 + lr] = a0.x; Ast[(lk + 1) * 128 + lr] = a0.y;
    Ast[(lk + 2) * 128 + lr] = a0.z; Ast[(lk + 3) * 128 + lr] = a0.w;
    Ast[(lk + 4) * 128 + lr] = a1.x; Ast[(lk + 5) * 128 + lr] = a1.y;
    Ast[(lk + 6) * 128 + lr] = a1.z; Ast[(lk + 7) * 128 + lr] = a1.w;
    Bst[(lk + 0) * 128 + lr] = b0.x; Bst[(lk + 1) * 128 + lr] = b0.y;
    Bst[(lk + 2) * 128 + lr] = b0.z; Bst[(lk + 3) * 128 + lr] = b0.w;
    Bst[(lk + 4) * 128 + lr] = b1.x; Bst[(lk + 5) * 128 + lr] = b1.y;
    Bst[(lk + 6) * 128 + lr] = b1.z; Bst[(lk + 7) * 128 + lr] = b1.w;
    __syncthreads();
#pragma unroll
    for (int k = 0; k < 16; ++k) {
      float4 aL = *(const float4*)&Ast[k * 128 + ry * 4];
      float4 aH = *(const float4*)&Ast[k * 128 + 64 + ry * 4];
      float4 bL = *(const float4*)&Bst[k * 128 + cx * 4];
      float4 bH = *(const float4*)&Bst[k * 128 + 64 + cx * 4];
      OP4(a00, aL, bL) OP4(a01, aL, bH) OP4(a10, aH, bL) OP4(a11, aH, bH)
    }
  }
#pragma unroll
  for (int rq = 0; rq < 2; ++rq) {
#pragma unroll
    for (int ii = 0; ii < 4; ++ii) {
      int r = row0 + rq * 64 + ry * 4 + ii;
#pragma unroll
      for (int cq = 0; cq < 2; ++cq) {
        int c = col0 + cq * 64 + cx * 4;
        size_t off = (size_t)r * N + c;
        float* ac = (rq == 0) ? (cq == 0 ? a00[ii] : a01[ii]) : (cq == 0 ? a10[ii] : a11[ii]);
        float4 v = make_float4(ac[0], ac[1], ac[2], ac[3]);
        if (EPI != 0) {
          float4 bb = *(const float4*)(bias + c);
          v.x += bb.x; v.y += bb.y; v.z += bb.z; v.w += bb.w;
        }
        if (EPI == 2) { v.x = gelu_f(v.x); v.y = gelu_f(v.y); v.z = gelu_f(v.z); v.w = gelu_f(v.w); }
        if (EPI == 3) {
          float4 rr = *(const float4*)(res + off);
          v.x += rr.x; v.y += rr.y; v.z += rr.z; v.w += rr.w;
        }
        *(float4*)(C + off) = v;
      }
    }
  }
}

// ---------------- flash attention fp32, conflict-free LDS layouts ----------------
// Qs[qrow][d] (stride 68, reads broadcast), KT[d][k] (stride 68, reads contiguous; reused as P[qrow][k]),
// Vs[k][d] (stride 64, reads contiguous).
#define AST 68
#define KST 68
__global__ __launch_bounds__(256) void attn_kernel(const float* __restrict__ qkv,
                                                   float* __restrict__ outp) {
  __shared__ __align__(16) float Qs[64 * AST];
  __shared__ __align__(16) float KT[64 * KST];
  __shared__ __align__(16) float Vs[64 * 64];
  int it = blockIdx.x, bh = blockIdx.y;
  int b = bh >> 3, h = bh & 7;
  int tid = threadIdx.x, ty = tid >> 4, tx = tid & 15;
  int i0 = it * 64;
  size_t rowbase = (size_t)b * LL;
  {
    int r = tid >> 2, c0 = (tid & 3) * 16;
    const float* src = qkv + (rowbase + i0 + r) * (3 * DM) + h * DH + c0;
#pragma unroll
    for (int j = 0; j < 4; ++j)
      *(float4*)&Qs[r * AST + c0 + 4 * j] = *(const float4*)(src + 4 * j);
  }
  float m_i[4], l_i[4], acc[4][4];
#pragma unroll
  for (int ii = 0; ii < 4; ++ii) {
    m_i[ii] = -INFINITY; l_i[ii] = 0.f;
#pragma unroll
    for (int jj = 0; jj < 4; ++jj) acc[ii][jj] = 0.f;
  }
  for (int jt = 0; jt < LL / 64; ++jt) {
    __syncthreads();  // previous iteration's P reads done; safe to overwrite KT/Vs
    {
      int r = tid >> 2, c0 = (tid & 3) * 16;   // r = key row, c0 = feature start
      const float* ksrc = qkv + (rowbase + jt * 64 + r) * (3 * DM) + DM + h * DH + c0;
      const float* vsrc = ksrc + DM;
#pragma unroll
      for (int j = 0; j < 4; ++j) {
        float4 kv = *(const float4*)(ksrc + 4 * j);
        *(float4*)&Vs[r * 64 + c0 + 4 * j] = *(const float4*)(vsrc + 4 * j);
        KT[(c0 + 4 * j + 0) * KST + r] = kv.x;
        KT[(c0 + 4 * j + 1) * KST + r] = kv.y;
        KT[(c0 + 4 * j + 2) * KST + r] = kv.z;
        KT[(c0 + 4 * j + 3) * KST + r] = kv.w;
      }
    }
    __syncthreads();
    float s[4][4] = {};
    for (int dd = 0; dd < 64; dd += 4) {
      float4 q0 = *(const float4*)&Qs[(ty * 4 + 0) * AST + dd];
      float4 q1 = *(const float4*)&Qs[(ty * 4 + 1) * AST + dd];
      float4 q2 = *(const float4*)&Qs[(ty * 4 + 2) * AST + dd];
      float4 q3 = *(const float4*)&Qs[(ty * 4 + 3) * AST + dd];
      float4 k0 = *(const float4*)&KT[(dd + 0) * KST + tx * 4];
      float4 k1 = *(const float4*)&KT[(dd + 1) * KST + tx * 4];
      float4 k2 = *(const float4*)&KT[(dd + 2) * KST + tx * 4];
      float4 k3 = *(const float4*)&KT[(dd + 3) * KST + tx * 4];
#define QKROW(ii, qq)                                                        \
      s[ii][0] += qq.x * k0.x + qq.y * k1.x + qq.z * k2.x + qq.w * k3.x;     \
      s[ii][1] += qq.x * k0.y + qq.y * k1.y + qq.z * k2.y + qq.w * k3.y;     \
      s[ii][2] += qq.x * k0.z + qq.y * k1.z + qq.z * k2.z + qq.w * k3.z;     \
      s[ii][3] += qq.x * k0.w + qq.y * k1.w + qq.z * k2.w + qq.w * k3.w;
      QKROW(0, q0) QKROW(1, q1) QKROW(2, q2) QKROW(3, q3)
#undef QKROW
    }
    float pr[4][4];
#pragma unroll
    for (int ii = 0; ii < 4; ++ii) {
      float mr = -INFINITY;
#pragma unroll
      for (int jj = 0; jj < 4; ++jj) { s[ii][jj] *= 0.125f; mr = fmaxf(mr, s[ii][jj]); }
      for (int m = 1; m < 16; m <<= 1) mr = fmaxf(mr, __shfl_xor(mr, m, 64));
      float mn = fmaxf(m_i[ii], mr);
      float alpha = expf(m_i[ii] - mn);
      float ps = 0.f;
#pragma unroll
      for (int jj = 0; jj < 4; ++jj) { float p = expf(s[ii][jj] - mn); pr[ii][jj] = p; ps += p; }
      for (int m = 1; m < 16; m <<= 1) ps += __shfl_xor(ps, m, 64);
      l_i[ii] = l_i[ii] * alpha + ps;
      m_i[ii] = mn;
#pragma unroll
      for (int jj = 0; jj < 4; ++jj) acc[ii][jj] *= alpha;
    }
    __syncthreads();  // all K reads done, safe to overwrite KT with P
#pragma unroll
    for (int ii = 0; ii < 4; ++ii)
      *(float4*)&KT[(ty * 4 + ii) * KST + tx * 4] =
          make_float4(pr[ii][0], pr[ii][1], pr[ii][2], pr[ii][3]);
    __syncthreads();
    for (int kk = 0; kk < 64; kk += 4) {
      float4 p0 = *(const float4*)&KT[(ty * 4 + 0) * KST + kk];
      float4 p1 = *(const float4*)&KT[(ty * 4 + 1) * KST + kk];
      float4 p2 = *(const float4*)&KT[(ty * 4 + 2) * KST + kk];
      float4 p3 = *(const float4*)&KT[(ty * 4 + 3) * KST + kk];
      float4 w0 = *(const float4*)&Vs[(kk + 0) * 64 + tx * 4];
      float4 w1 = *(const float4*)&Vs[(kk + 1) * 64 + tx * 4];
      float4 w2 = *(const float4*)&Vs[(kk + 2) * 64 + tx * 4];
      float4 w3 = *(const float4*)&Vs[(kk + 3) * 64 + tx * 4];
#define PVROW(ii, pp)                                                      \
      acc[ii][0] += pp.x * w0.x + pp.y * w1.x + pp.z * w2.x + pp.w * w3.x; \
      acc[ii][1] += pp.x * w0.y + pp.y * w1.y + pp.z * w2.y + pp.w * w3.y; \
      acc[ii][2] += pp.x * w0.z + pp.y * w1.z + pp.z * w2.z + pp.w * w3.z; \
      acc[ii][3] += pp.x * w0.w + pp.y * w1.w + pp.z * w2.w + pp.w * w3.w;
      PVROW(0, p0) PVROW(1, p1) PVROW(2, p2) PVROW(3, p3)
#undef PVROW
    }
  }
#pragma unroll
  for (int ii = 0; ii < 4; ++ii) {
    float inv = 1.0f / l_i[ii];
    *(float4*)(outp + (rowbase + i0 + ty * 4 + ii) * DM + h * DH + tx * 4) =
        make_float4(acc[ii][0] * inv, acc[ii][1] * inv, acc[ii][2] * inv, acc[ii][3] * inv);
  }
}

// ---------------- max-pool over sequence (two stage) ----------------
__global__ __launch_bounds__(256) void poolmax1_kernel(const float* __restrict__ x,
                                                       float* __restrict__ partial) {
  int ch = blockIdx.x, b = blockIdx.y, tid = threadIdx.x;
  const float* p = x + ((size_t)b * LL + ch * 128) * DM;
  float m0 = -INFINITY, m1 = -INFINITY;
#pragma unroll 4
  for (int l = 0; l < 128; ++l) {
    m0 = fmaxf(m0, p[(size_t)l * DM + tid]);
    m1 = fmaxf(m1, p[(size_t)l * DM + tid + 256]);
  }
  partial[(size_t)(b * TO + ch) * DM + tid] = m0;
  partial[(size_t)(b * TO + ch) * DM + tid + 256] = m1;
}

__global__ __launch_bounds__(256) void poolmax2_kernel(const float* __restrict__ partial,
                                                       float* __restrict__ pooled) {
  int idx = blockIdx.x * 256 + threadIdx.x;  // < BN_*DM
  int b = idx >> 9, d = idx & 511;
  float m = -INFINITY;
#pragma unroll
  for (int c = 0; c < TO; ++c) m = fmaxf(m, partial[(size_t)(b * TO + c) * DM + d]);
  pooled[idx] = m;
}

// ---------------- head MLP ----------------
__global__ __launch_bounds__(256) void head1_kernel(const float* __restrict__ lnp,
                                                    const float* __restrict__ w,
                                                    const float* __restrict__ bb,
                                                    float* __restrict__ hid) {
  int idx = blockIdx.x * 256 + threadIdx.x;  // < BN_*MLPD
  int b = idx >> 10, n = idx & 1023;
  const float* xr = lnp + (size_t)b * DM;
  const float* wr = w + (size_t)n * DM;
  float s = 0.f;
  for (int k = 0; k < DM; k += 4) {
    float4 xv = *(const float4*)(xr + k);
    float4 wv = *(const float4*)(wr + k);
    s += xv.x * wv.x + xv.y * wv.y + xv.z * wv.z + xv.w * wv.w;
  }
  hid[idx] = gelu_f(s + bb[n]);
}

__global__ __launch_bounds__(128) void head2_kernel(const float* __restrict__ hid,
                                                    const float* __restrict__ w,
                                                    const float* __restrict__ bb,
                                                    float* __restrict__ dout) {
  int t = threadIdx.x;
  if (t < BN_ * NC) {
    int b = t / NC, n = t - b * NC;
    const float* xr = hid + (size_t)b * MLPD;
    const float* wr = w + (size_t)n * MLPD;
    float s = 0.f;
    for (int k = 0; k < MLPD; k += 4) {
      float4 xv = *(const float4*)(xr + k);
      float4 wv = *(const float4*)(wr + k);
      s += xv.x * wv.x + xv.y * wv.y + xv.z * wv.z + xv.w * wv.w;
    }
    dout[OUT_LOGITS + t] = s + bb[n];
  }
}

// ---------------- launch ----------------
extern "C" void kernel_launch(void* const* d_in, const int* in_sizes, int n_in,
                              void* d_out, int out_size, void* d_ws, size_t ws_size,
                              hipStream_t stream) {
  (void)in_sizes; (void)n_in; (void)out_size; (void)ws_size;
  const float* xyzs     = (const float*)d_in[0];
  const float* oldf     = (const float*)d_in[1];
  const float* conv_d_w = (const float*)d_in[2];
  const float* conv_f_w = (const float*)d_in[3];
  const float* pos_w    = (const float*)d_in[4];
  const float* pos_b    = (const float*)d_in[5];
  const float* contr_w  = (const float*)d_in[6];
  const float* contr_b  = (const float*)d_in[7];
  const float* ln1_s    = (const float*)d_in[8];
  const float* ln1_b    = (const float*)d_in[9];
  const float* qkv_w    = (const float*)d_in[10];
  const float* out_w    = (const float*)d_in[11];
  const float* out_b    = (const float*)d_in[12];
  const float* ln2_s    = (const float*)d_in[13];
  const float* ln2_b    = (const float*)d_in[14];
  const float* ff1_w    = (const float*)d_in[15];
  const float* ff1_b    = (const float*)d_in[16];
  const float* ff2_w    = (const float*)d_in[17];
  const float* ff2_b    = (const float*)d_in[18];
  const float* hl_s     = (const float*)d_in[19];
  const float* hl_b     = (const float*)d_in[20];
  const float* h1_w     = (const float*)d_in[21];
  const float* h1_b     = (const float*)d_in[22];
  const float* h2_w     = (const float*)d_in[23];
  const float* h2_b     = (const float*)d_in[24];
  float* dout = (float*)d_out;
  float* ws = (float*)d_ws;

  size_t off = 0;
  float* anchor = ws + off; off += (size_t)BN_ * TO * MM * 3;
  off = (off + 63) & ~(size_t)63;
  float* x     = ws + off; off += (size_t)BL * DM;
  float* hbuf  = ws + off; off += (size_t)BL * DM;
  float* qkvb  = ws + off; off += (size_t)BL * 3 * DM;
  float* attno = ws + off; off += (size_t)BL * DM;
  float* partial = ws + off; off += (size_t)BN_ * TO * DM;
  float* pooled = ws + off; off += BN_ * DM;
  float* lnp    = ws + off; off += BN_ * DM;
  float* hid    = ws + off; off += BN_ * MLPD;
  float* ffb = qkvb;  // reuse qkv buffer for FF hidden

  fps_kernel<<<BN_ * TO, 256, 0, stream>>>(xyzs, anchor);
  ballconv_kernel<<<BN_ * TO * MM, 64, 0, stream>>>(xyzs, oldf, anchor, conv_d_w, conv_f_w, dout);
  posx_kernel<<<(BL * DM) / 256, 256, 0, stream>>>(anchor, pos_w, pos_b, contr_w, contr_b, dout, x);

  for (int l = 0; l < 4; ++l) {
    ln_kernel<<<BL, 64, 0, stream>>>(x, ln1_s + l * DM, ln1_b + l * DM, hbuf);
    gemm_kernel<0><<<dim3(3 * DM / 128, BL / 128), 256, 0, stream>>>(
        hbuf, qkv_w + (size_t)l * 3 * DM * DM, nullptr, nullptr, qkvb, BL, 3 * DM, DM);
    attn_kernel<<<dim3(LL / 64, BN_ * NH), 256, 0, stream>>>(qkvb, attno);
    gemm_kernel<3><<<dim3(DM / 128, BL / 128), 256, 0, stream>>>(
        attno, out_w + (size_t)l * DM * DM, out_b + l * DM, x, x, BL, DM, DM);
    ln_kernel<<<BL, 64, 0, stream>>>(x, ln2_s + l * DM, ln2_b + l * DM, hbuf);
    gemm_kernel<2><<<dim3(MLPD / 128, BL / 128), 256, 0, stream>>>(
        hbuf, ff1_w + (size_t)l * MLPD * DM, ff1_b + l * MLPD, nullptr, ffb, BL, MLPD, DM);
    gemm_kernel<3><<<dim3(DM / 128, BL / 128), 256, 0, stream>>>(
        ffb, ff2_w + (size_t)l * DM * MLPD, ff2_b + l * DM, x, x, BL, DM, MLPD);
  }

  poolmax1_kernel<<<dim3(TO, BN_), 256, 0, stream>>>(x, partial);
  poolmax2_kernel<<<(BN_ * DM) / 256, 256, 0, stream>>>(partial, pooled);
  ln_kernel<<<BN_, 64, 0, stream>>>(pooled, hl_s, hl_b, lnp);
  head1_kernel<<<(BN_ * MLPD) / 256, 256, 0, stream>>>(lnp, h1_w, h1_b, hid);
  head2_kernel<<<1, 128, 0, stream>>>(hid, h2_w, h2_b, dout);
}

// Round 3
// 1651.016 us; speedup vs baseline: 2.4439x; 2.2592x over previous
//
#include <hip/hip_runtime.h>
#include <math.h>

// ---------------- problem constants ----------------
#define BN_  4
#define TT   24
#define NN   4096
#define TO   12
#define MM   128
#define LL   (TO*MM)          // 1536
#define BL   (BN_*LL)         // 6144
#define DM   512
#define NH   8
#define DH   64
#define MLPD 1024
#define NC   30

// output layout (floats): logits | contrastive | features
#define OUT_LOGITS 0
#define OUT_CONTR  (BN_*NC)                 // 120
#define OUT_FEATS  (OUT_CONTR + BL*DM)      // 120 + 3145728

typedef __attribute__((ext_vector_type(8))) short s16x8;
typedef __attribute__((ext_vector_type(4))) float f32x4;
#define MFMA(a,b,c) __builtin_amdgcn_mfma_f32_16x16x32_bf16(a,b,c,0,0,0)

// split fp32 -> bf16 hi (truncate) + bf16 lo (truncated residual); a ~= hi + lo
__device__ __forceinline__ void split_bf16(float a, short &h, short &l) {
  unsigned u = __float_as_uint(a);
  h = (short)(u >> 16);
  float ah = __uint_as_float(u & 0xffff0000u);
  float al = a - ah;
  l = (short)(__float_as_uint(al) >> 16);
}

__device__ __forceinline__ void split8(float4 a, float4 b, s16x8 &h8, s16x8 &l8) {
  short h, l;
  split_bf16(a.x,h,l); h8[0]=h; l8[0]=l;
  split_bf16(a.y,h,l); h8[1]=h; l8[1]=l;
  split_bf16(a.z,h,l); h8[2]=h; l8[2]=l;
  split_bf16(a.w,h,l); h8[3]=h; l8[3]=l;
  split_bf16(b.x,h,l); h8[4]=h; l8[4]=l;
  split_bf16(b.y,h,l); h8[5]=h; l8[5]=l;
  split_bf16(b.z,h,l); h8[6]=h; l8[6]=l;
  split_bf16(b.w,h,l); h8[7]=h; l8[7]=l;
}

// exact (non-FMA-contracted) squared distance, matching XLA's mul+add order
__device__ __forceinline__ float d2_3(float ax, float ay, float az,
                                      float bx, float by, float bz) {
#pragma clang fp contract(off)
  float dx = ax - bx, dy = ay - by, dz = az - bz;
  float dx2 = dx * dx, dy2 = dy * dy, dz2 = dz * dz;
  return (dx2 + dy2) + dz2;
}

__device__ __forceinline__ float gelu_f(float v) {
  return 0.5f * v * (1.0f + erff(v * 0.70710678118654752440f));
}

// ---------------- FPS: one block per (b, ti) ----------------
__global__ __launch_bounds__(256) void fps_kernel(const float* __restrict__ xyzs,
                                                  float* __restrict__ anchor) {
  __shared__ float sx[NN], sy[NN], sz[NN];
  __shared__ float swv[4];
  __shared__ int   swi[4];
  __shared__ int   s_next;
  int blk = blockIdx.x;
  int b = blk / TO, ti = blk - b * TO;
  int frame = 2 * ti;
  const float* src = xyzs + ((size_t)(b * TT + frame)) * NN * 3;
  int tid = threadIdx.x;
  float dist[16], px[16], py[16], pz[16];
#pragma unroll
  for (int s = 0; s < 16; ++s) {
    int p = tid + s * 256;
    px[s] = src[p * 3 + 0]; py[s] = src[p * 3 + 1]; pz[s] = src[p * 3 + 2];
    sx[p] = px[s]; sy[p] = py[s]; sz[p] = pz[s];
    dist[s] = 1e10f;
  }
  __syncthreads();
  float lx = sx[0], ly = sy[0], lz = sz[0];
  float* aout = anchor + (size_t)blk * MM * 3;
  if (tid == 0) { aout[0] = lx; aout[1] = ly; aout[2] = lz; }
  for (int j = 1; j < MM; ++j) {
    float bestv = -1.0f; int besti = 0;
#pragma unroll
    for (int s = 0; s < 16; ++s) {
      float d2 = d2_3(px[s], py[s], pz[s], lx, ly, lz);
      float dn = fminf(dist[s], d2);
      dist[s] = dn;
      if (dn > bestv) { bestv = dn; besti = tid + s * 256; }
    }
    for (int m = 1; m < 64; m <<= 1) {
      float ov = __shfl_xor(bestv, m, 64);
      int   oi = __shfl_xor(besti, m, 64);
      if (ov > bestv || (ov == bestv && oi < besti)) { bestv = ov; besti = oi; }
    }
    if ((tid & 63) == 0) { swv[tid >> 6] = bestv; swi[tid >> 6] = besti; }
    __syncthreads();
    if (tid == 0) {
      float bv = swv[0]; int bi = swi[0];
      for (int q = 1; q < 4; ++q)
        if (swv[q] > bv || (swv[q] == bv && swi[q] < bi)) { bv = swv[q]; bi = swi[q]; }
      s_next = bi;
      aout[j * 3 + 0] = sx[bi]; aout[j * 3 + 1] = sy[bi]; aout[j * 3 + 2] = sz[bi];
    }
    __syncthreads();
    int nxt = s_next;
    lx = sx[nxt]; ly = sy[nxt]; lz = sz[nxt];
  }
}

// ---------------- ball query + p4dconv + max-pool: one wave per (b,ti,m) ----------------
__global__ __launch_bounds__(64) void ballconv_kernel(
    const float* __restrict__ xyzs, const float* __restrict__ oldf,
    const float* __restrict__ anchor,
    const float* __restrict__ wdw, const float* __restrict__ wfw,
    float* __restrict__ dout) {
  __shared__ int   sidx[32];
  __shared__ float sdisp[32][4];
  __shared__ float sfeat[32][2];
  int blk = blockIdx.x;
  int b = blk / (TO * MM);
  int rem = blk - b * (TO * MM);
  int ti = rem / MM;
  int lane = threadIdx.x;
  const float* ap = anchor + (size_t)blk * 3;
  float ax = ap[0], ay = ap[1], az = ap[2];
  int d0 = lane * 8;
  float4 wd[8]; float2 wf[8];
#pragma unroll
  for (int jd = 0; jd < 8; ++jd) {
    wd[jd] = *(const float4*)(wdw + (d0 + jd) * 4);
    wf[jd] = *(const float2*)(wfw + (d0 + jd) * 2);
  }
  float fmx[8];
#pragma unroll
  for (int jd = 0; jd < 8; ++jd) fmx[jd] = -INFINITY;

  for (int o = -1; o <= 1; ++o) {
    int tp = 1 + 2 * ti + o;
    int orig = (tp == 0) ? 0 : tp - 1;
    const float* nx = xyzs + ((size_t)(b * TT + orig)) * NN * 3;
    const float* nf = oldf + ((size_t)(b * TT + orig)) * 2 * NN;
    int cnt = 0;
    for (int base = 0; base < NN && cnt < 32; base += 64) {
      int p = base + lane;
      float d2 = d2_3(ax, ay, az, nx[p * 3], nx[p * 3 + 1], nx[p * 3 + 2]);
      bool in = d2 < 0.09f;
      unsigned long long mask = __ballot(in);
      int pos = __popcll(mask & ((1ull << lane) - 1ull));
      if (in && (cnt + pos) < 32) sidx[cnt + pos] = p;
      cnt += __popcll(mask);
    }
    __syncthreads();
    int used = cnt < 32 ? cnt : 32;
    if (lane < 32 && lane >= used) sidx[lane] = (used > 0) ? sidx[0] : 0;
    __syncthreads();
    if (lane < 32) {
      int p = sidx[lane];
      sdisp[lane][0] = nx[p * 3 + 0] - ax;
      sdisp[lane][1] = nx[p * 3 + 1] - ay;
      sdisp[lane][2] = nx[p * 3 + 2] - az;
      sdisp[lane][3] = (float)o;
      sfeat[lane][0] = nf[p];
      sfeat[lane][1] = nf[NN + p];
    }
    __syncthreads();
    for (int k = 0; k < 32; ++k) {
      float p0 = sdisp[k][0], p1 = sdisp[k][1], p2 = sdisp[k][2], p3 = sdisp[k][3];
      float f0 = sfeat[k][0], f1 = sfeat[k][1];
#pragma unroll
      for (int jd = 0; jd < 8; ++jd) {
        float de = wd[jd].x * p0 + wd[jd].y * p1 + wd[jd].z * p2 + wd[jd].w * p3;
        float fe = wf[jd].x * f0 + wf[jd].y * f1;
        fmx[jd] = fmaxf(fmx[jd], fe * de);
      }
    }
    __syncthreads();
  }
  float* fout = dout + OUT_FEATS + (size_t)blk * DM + d0;
#pragma unroll
  for (int jd = 0; jd < 8; jd += 4)
    *(float4*)(fout + jd) = make_float4(fmx[jd], fmx[jd + 1], fmx[jd + 2], fmx[jd + 3]);
}

// ---------------- pos/contrastive embed + x = relu(pos + features) ----------------
__global__ __launch_bounds__(256) void posx_kernel(
    const float* __restrict__ anchor,
    const float* __restrict__ pw, const float* __restrict__ pb,
    const float* __restrict__ cw, const float* __restrict__ cb,
    float* __restrict__ dout, float* __restrict__ x) {
  int idx = blockIdx.x * 256 + threadIdx.x;
  int bl = idx >> 9, d = idx & 511;
  int ti = (bl % LL) / MM;
  const float* ap = anchor + (size_t)bl * 3;
  float c0 = ap[0], c1 = ap[1], c2 = ap[2], c3 = (float)(ti + 1);
  float4 pwv = *(const float4*)(pw + d * 4);
  float4 cwv = *(const float4*)(cw + d * 4);
  float pos = pwv.x * c0 + pwv.y * c1 + pwv.z * c2 + pwv.w * c3 + pb[d];
  float con = cwv.x * c0 + cwv.y * c1 + cwv.z * c2 + cwv.w * c3 + cb[d];
  dout[OUT_CONTR + (size_t)idx] = con;
  float v = pos + dout[OUT_FEATS + (size_t)idx];
  x[idx] = v > 0.0f ? v : 0.0f;
}

// ---------------- LayerNorm -> split bf16 hi/lo: one wave per row ----------------
__global__ __launch_bounds__(64) void ln_split_kernel(
    const float* __restrict__ x, const float* __restrict__ gs,
    const float* __restrict__ gb, short* __restrict__ oh, short* __restrict__ ol) {
  int row = blockIdx.x, lane = threadIdx.x;
  const float* xr = x + (size_t)row * DM + lane * 8;
  float4 v0 = *(const float4*)xr;
  float4 v1 = *(const float4*)(xr + 4);
  float v[8] = {v0.x, v0.y, v0.z, v0.w, v1.x, v1.y, v1.z, v1.w};
  float s = 0.f;
#pragma unroll
  for (int j = 0; j < 8; ++j) s += v[j];
  for (int m = 1; m < 64; m <<= 1) s += __shfl_xor(s, m, 64);
  float mu = s * (1.0f / DM);
  float d[8], ss = 0.f;
#pragma unroll
  for (int j = 0; j < 8; ++j) { d[j] = v[j] - mu; ss += d[j] * d[j]; }
  for (int m = 1; m < 64; m <<= 1) ss += __shfl_xor(ss, m, 64);
  float rs = 1.0f / sqrtf(ss * (1.0f / DM) + 1e-5f);
  const float* gsr = gs + lane * 8;
  const float* gbr = gb + lane * 8;
  s16x8 hv, lv;
#pragma unroll
  for (int j = 0; j < 8; ++j) {
    float f = d[j] * rs * gsr[j] + gbr[j];
    short h, l; split_bf16(f, h, l);
    hv[j] = h; lv[j] = l;
  }
  *(s16x8*)(oh + (size_t)row * DM + lane * 8) = hv;
  *(s16x8*)(ol + (size_t)row * DM + lane * 8) = lv;
}

// ---------------- LayerNorm fp32 out (head path) ----------------
__global__ __launch_bounds__(64) void ln_kernel(
    const float* __restrict__ x, const float* __restrict__ gs,
    const float* __restrict__ gb, float* __restrict__ out) {
  int row = blockIdx.x, lane = threadIdx.x;
  const float* xr = x + (size_t)row * DM + lane * 8;
  float4 v0 = *(const float4*)xr;
  float4 v1 = *(const float4*)(xr + 4);
  float v[8] = {v0.x, v0.y, v0.z, v0.w, v1.x, v1.y, v1.z, v1.w};
  float s = 0.f;
#pragma unroll
  for (int j = 0; j < 8; ++j) s += v[j];
  for (int m = 1; m < 64; m <<= 1) s += __shfl_xor(s, m, 64);
  float mu = s * (1.0f / DM);
  float d[8], ss = 0.f;
#pragma unroll
  for (int j = 0; j < 8; ++j) { d[j] = v[j] - mu; ss += d[j] * d[j]; }
  for (int m = 1; m < 64; m <<= 1) ss += __shfl_xor(ss, m, 64);
  float rs = 1.0f / sqrtf(ss * (1.0f / DM) + 1e-5f);
  const float* gsr = gs + lane * 8;
  const float* gbr = gb + lane * 8;
  float* orow = out + (size_t)row * DM + lane * 8;
  float r[8];
#pragma unroll
  for (int j = 0; j < 8; ++j) r[j] = d[j] * rs * gsr[j] + gbr[j];
  *(float4*)orow       = make_float4(r[0], r[1], r[2], r[3]);
  *(float4*)(orow + 4) = make_float4(r[4], r[5], r[6], r[7]);
}

// ---------------- split-bf16 MFMA GEMM 128x128: C = A(MxK) * W(NxK)^T ----------------
// A pre-split (Ah/Al bf16 bits), W fp32 split in-kernel.
// EPI: 1 = split-out (no bias), 2 = bias+gelu+split-out, 3 = bias+residual, fp32 out
template <int EPI>
__global__ __launch_bounds__(256) void mgemm_kernel(
    const short* __restrict__ Ah, const short* __restrict__ Al,
    const float* __restrict__ W,
    const float* __restrict__ bias, const float* __restrict__ res,
    float* __restrict__ Cf, short* __restrict__ Ch, short* __restrict__ Cl,
    int M, int N, int K) {
  __shared__ short As[2][128 * 40];   // [hi/lo][row][k(32)+pad8]
  __shared__ short Ws[2][128 * 40];
  int tid = threadIdx.x;
  int lane = tid & 63, w = tid >> 6;
  int wr = w >> 1, wc = w & 1;
  int row0 = blockIdx.y * 128, col0 = blockIdx.x * 128;
  int srow = tid >> 1, skc = (tid & 1) * 16;
  const short* Ahp = Ah + (size_t)(row0 + srow) * K + skc;
  const short* Alp = Al + (size_t)(row0 + srow) * K + skc;
  const float* Wp  = W  + (size_t)(col0 + srow) * K + skc;
  int fr = lane & 15, fk = (lane >> 4) * 8;
  f32x4 acc[16];
#pragma unroll
  for (int i = 0; i < 16; ++i) acc[i] = (f32x4){0.f, 0.f, 0.f, 0.f};
  // prologue: prefetch first K-step
  s16x8 rA0 = *(const s16x8*)(Ahp);
  s16x8 rA1 = *(const s16x8*)(Ahp + 8);
  s16x8 rA2 = *(const s16x8*)(Alp);
  s16x8 rA3 = *(const s16x8*)(Alp + 8);
  float4 rW0 = *(const float4*)(Wp);
  float4 rW1 = *(const float4*)(Wp + 4);
  float4 rW2 = *(const float4*)(Wp + 8);
  float4 rW3 = *(const float4*)(Wp + 12);
  for (int ks = 0; ks < K; ks += 32) {
    __syncthreads();
    *(s16x8*)&As[0][srow * 40 + skc]     = rA0;
    *(s16x8*)&As[0][srow * 40 + skc + 8] = rA1;
    *(s16x8*)&As[1][srow * 40 + skc]     = rA2;
    *(s16x8*)&As[1][srow * 40 + skc + 8] = rA3;
    s16x8 wh0, wl0, wh1, wl1;
    split8(rW0, rW1, wh0, wl0);
    split8(rW2, rW3, wh1, wl1);
    *(s16x8*)&Ws[0][srow * 40 + skc]     = wh0;
    *(s16x8*)&Ws[0][srow * 40 + skc + 8] = wh1;
    *(s16x8*)&Ws[1][srow * 40 + skc]     = wl0;
    *(s16x8*)&Ws[1][srow * 40 + skc + 8] = wl1;
    __syncthreads();
    if (ks + 32 < K) {  // prefetch next K-step (hides latency under MFMAs)
      rA0 = *(const s16x8*)(Ahp + ks + 32);
      rA1 = *(const s16x8*)(Ahp + ks + 40);
      rA2 = *(const s16x8*)(Alp + ks + 32);
      rA3 = *(const s16x8*)(Alp + ks + 40);
      rW0 = *(const float4*)(Wp + ks + 32);
      rW1 = *(const float4*)(Wp + ks + 36);
      rW2 = *(const float4*)(Wp + ks + 40);
      rW3 = *(const float4*)(Wp + ks + 44);
    }
    s16x8 bh_[4], bl_[4];
#pragma unroll
    for (int t = 0; t < 4; ++t) {
      bh_[t] = *(const s16x8*)&Ws[0][(wc * 64 + t * 16 + fr) * 40 + fk];
      bl_[t] = *(const s16x8*)&Ws[1][(wc * 64 + t * 16 + fr) * 40 + fk];
    }
#pragma unroll
    for (int a = 0; a < 4; ++a) {
      s16x8 ah_ = *(const s16x8*)&As[0][(wr * 64 + a * 16 + fr) * 40 + fk];
      s16x8 al_ = *(const s16x8*)&As[1][(wr * 64 + a * 16 + fr) * 40 + fk];
#pragma unroll
      for (int t = 0; t < 4; ++t) {
        f32x4 c = acc[a * 4 + t];
        c = MFMA(ah_, bh_[t], c);
        c = MFMA(ah_, bl_[t], c);
        c = MFMA(al_, bh_[t], c);
        acc[a * 4 + t] = c;
      }
    }
  }
  int fq = lane >> 4;
#pragma unroll
  for (int a = 0; a < 4; ++a) {
#pragma unroll
    for (int t = 0; t < 4; ++t) {
#pragma unroll
      for (int r = 0; r < 4; ++r) {
        int row = row0 + wr * 64 + a * 16 + fq * 4 + r;
        int c   = col0 + wc * 64 + t * 16 + fr;
        size_t off = (size_t)row * N + c;
        float v = acc[a * 4 + t][r];
        if (EPI >= 2) v += bias[c];
        if (EPI == 2) {
          v = gelu_f(v);
          short h, l; split_bf16(v, h, l);
          Ch[off] = h; Cl[off] = l;
        } else if (EPI == 3) {
          v += res[off];
          Cf[off] = v;
        } else {
          short h, l; split_bf16(v, h, l);
          Ch[off] = h; Cl[off] = l;
        }
      }
    }
  }
}

// ---------------- split-bf16 MFMA flash attention ----------------
// 256 thr = 4 waves; wave w owns Q-rows [it*64+16w, +16). K row-major then V^T share KV LDS.
__global__ __launch_bounds__(256) void mattn_kernel(
    const short* __restrict__ qh, const short* __restrict__ ql,
    short* __restrict__ oh, short* __restrict__ ol) {
  __shared__ short KV[2][64 * 72];
  __shared__ short Ps[2][64 * 72];
  int it = blockIdx.x, bh = blockIdx.y;
  int b = bh >> 3, h = bh & 7;
  int tid = threadIdx.x, lane = tid & 63, w = tid >> 6;
  int fr = lane & 15, fq = lane >> 4, fk = fq * 8;
  size_t rowbase = (size_t)b * LL;
  const int QS = 3 * DM;
  // Q fragments in registers (hi/lo, 2 k-steps)
  s16x8 qfh[2], qfl[2];
  {
    size_t qoff = (size_t)(rowbase + it * 64 + w * 16 + fr) * QS + h * DH;
    qfh[0] = *(const s16x8*)(qh + qoff + fk);
    qfh[1] = *(const s16x8*)(qh + qoff + 32 + fk);
    qfl[0] = *(const s16x8*)(ql + qoff + fk);
    qfl[1] = *(const s16x8*)(ql + qoff + 32 + fk);
  }
  float m_i[4], l_i[4];
  f32x4 oac[4];
#pragma unroll
  for (int r = 0; r < 4; ++r) { m_i[r] = -INFINITY; l_i[r] = 0.f; }
#pragma unroll
  for (int t = 0; t < 4; ++t) oac[t] = (f32x4){0.f, 0.f, 0.f, 0.f};
  int kjr = tid >> 2, kc0 = (tid & 3) * 16;   // K staging map
  int vd = tid & 63, vj0 = (tid >> 6) * 16;   // V^T staging map
  for (int jt = 0; jt < LL / 64; ++jt) {
    // K tile prefetch (issued before barrier)
    size_t kbase = (size_t)(rowbase + jt * 64 + kjr) * QS + DM + h * DH + kc0;
    s16x8 k0 = *(const s16x8*)(qh + kbase);
    s16x8 k1 = *(const s16x8*)(qh + kbase + 8);
    s16x8 k2 = *(const s16x8*)(ql + kbase);
    s16x8 k3 = *(const s16x8*)(ql + kbase + 8);
    __syncthreads();   // prev PV V-reads done
    *(s16x8*)&KV[0][kjr * 72 + kc0]     = k0;
    *(s16x8*)&KV[0][kjr * 72 + kc0 + 8] = k1;
    *(s16x8*)&KV[1][kjr * 72 + kc0]     = k2;
    *(s16x8*)&KV[1][kjr * 72 + kc0 + 8] = k3;
    __syncthreads();
    // QK^T
    f32x4 s[4];
#pragma unroll
    for (int t = 0; t < 4; ++t) s[t] = (f32x4){0.f, 0.f, 0.f, 0.f};
#pragma unroll
    for (int ks = 0; ks < 2; ++ks) {
#pragma unroll
      for (int t = 0; t < 4; ++t) {
        s16x8 kh_ = *(const s16x8*)&KV[0][(t * 16 + fr) * 72 + ks * 32 + fk];
        s16x8 kl_ = *(const s16x8*)&KV[1][(t * 16 + fr) * 72 + ks * 32 + fk];
        s[t] = MFMA(qfh[ks], kh_, s[t]);
        s[t] = MFMA(qfh[ks], kl_, s[t]);
        s[t] = MFMA(qfl[ks], kh_, s[t]);
      }
    }
    // V^T prefetch from global (latency overlaps softmax VALU)
    size_t vbase = (size_t)(rowbase + jt * 64 + vj0) * QS + 2 * DM + h * DH + vd;
    s16x8 vh0, vh1, vl0, vl1;
#pragma unroll
    for (int q = 0; q < 8; ++q) {
      vh0[q] = qh[vbase + (size_t)q * QS];
      vh1[q] = qh[vbase + (size_t)(q + 8) * QS];
      vl0[q] = ql[vbase + (size_t)q * QS];
      vl1[q] = ql[vbase + (size_t)(q + 8) * QS];
    }
    // online softmax (rows = 4*fq + r, cols across 16 lanes x 4 tiles)
#pragma unroll
    for (int r = 0; r < 4; ++r) {
      float s0 = s[0][r] * 0.125f, s1 = s[1][r] * 0.125f;
      float s2 = s[2][r] * 0.125f, s3 = s[3][r] * 0.125f;
      float mr = fmaxf(fmaxf(s0, s1), fmaxf(s2, s3));
      mr = fmaxf(mr, __shfl_xor(mr, 1, 64));
      mr = fmaxf(mr, __shfl_xor(mr, 2, 64));
      mr = fmaxf(mr, __shfl_xor(mr, 4, 64));
      mr = fmaxf(mr, __shfl_xor(mr, 8, 64));
      float mn = fmaxf(m_i[r], mr);
      float al = expf(m_i[r] - mn);
      float p0 = expf(s0 - mn), p1 = expf(s1 - mn);
      float p2 = expf(s2 - mn), p3 = expf(s3 - mn);
      float ps = p0 + p1 + p2 + p3;
      ps += __shfl_xor(ps, 1, 64); ps += __shfl_xor(ps, 2, 64);
      ps += __shfl_xor(ps, 4, 64); ps += __shfl_xor(ps, 8, 64);
      l_i[r] = l_i[r] * al + ps;
      m_i[r] = mn;
      oac[0][r] *= al; oac[1][r] *= al; oac[2][r] *= al; oac[3][r] *= al;
      int prow = (w * 16 + fq * 4 + r) * 72;
      short hh, ll;
      split_bf16(p0, hh, ll); Ps[0][prow + fr]      = hh; Ps[1][prow + fr]      = ll;
      split_bf16(p1, hh, ll); Ps[0][prow + 16 + fr] = hh; Ps[1][prow + 16 + fr] = ll;
      split_bf16(p2, hh, ll); Ps[0][prow + 32 + fr] = hh; Ps[1][prow + 32 + fr] = ll;
      split_bf16(p3, hh, ll); Ps[0][prow + 48 + fr] = hh; Ps[1][prow + 48 + fr] = ll;
    }
    __syncthreads();   // all K reads done -> overwrite KV with V^T
    *(s16x8*)&KV[0][vd * 72 + vj0]     = vh0;
    *(s16x8*)&KV[0][vd * 72 + vj0 + 8] = vh1;
    *(s16x8*)&KV[1][vd * 72 + vj0]     = vl0;
    *(s16x8*)&KV[1][vd * 72 + vj0 + 8] = vl1;
    __syncthreads();
    // PV: O[i][d] += P[i][j] V[j][d], B-operand = V^T rows (d), k = j
#pragma unroll
    for (int ks = 0; ks < 2; ++ks) {
      s16x8 ph_ = *(const s16x8*)&Ps[0][(w * 16 + fr) * 72 + ks * 32 + fk];
      s16x8 pl_ = *(const s16x8*)&Ps[1][(w * 16 + fr) * 72 + ks * 32 + fk];
#pragma unroll
      for (int t = 0; t < 4; ++t) {
        s16x8 vh_ = *(const s16x8*)&KV[0][(t * 16 + fr) * 72 + ks * 32 + fk];
        s16x8 vl_ = *(const s16x8*)&KV[1][(t * 16 + fr) * 72 + ks * 32 + fk];
        oac[t] = MFMA(ph_, vh_, oac[t]);
        oac[t] = MFMA(ph_, vl_, oac[t]);
        oac[t] = MFMA(pl_, vh_, oac[t]);
      }
    }
  }
#pragma unroll
  for (int r = 0; r < 4; ++r) {
    float inv = 1.0f / l_i[r];
    size_t row = rowbase + it * 64 + w * 16 + fq * 4 + r;
#pragma unroll
    for (int t = 0; t < 4; ++t) {
      float v = oac[t][r] * inv;
      short hh, ll; split_bf16(v, hh, ll);
      size_t off = row * DM + h * DH + t * 16 + fr;
      oh[off] = hh; ol[off] = ll;
    }
  }
}

// ---------------- max-pool over sequence (two stage) ----------------
__global__ __launch_bounds__(256) void poolmax1_kernel(const float* __restrict__ x,
                                                       float* __restrict__ partial) {
  int ch = blockIdx.x, b = blockIdx.y, tid = threadIdx.x;
  const float* p = x + ((size_t)b * LL + ch * 128) * DM;
  float m0 = -INFINITY, m1 = -INFINITY;
#pragma unroll 4
  for (int l = 0; l < 128; ++l) {
    m0 = fmaxf(m0, p[(size_t)l * DM + tid]);
    m1 = fmaxf(m1, p[(size_t)l * DM + tid + 256]);
  }
  partial[(size_t)(b * TO + ch) * DM + tid] = m0;
  partial[(size_t)(b * TO + ch) * DM + tid + 256] = m1;
}

__global__ __launch_bounds__(256) void poolmax2_kernel(const float* __restrict__ partial,
                                                       float* __restrict__ pooled) {
  int idx = blockIdx.x * 256 + threadIdx.x;
  int b = idx >> 9, d = idx & 511;
  float m = -INFINITY;
#pragma unroll
  for (int c = 0; c < TO; ++c) m = fmaxf(m, partial[(size_t)(b * TO + c) * DM + d]);
  pooled[idx] = m;
}

// ---------------- head MLP ----------------
__global__ __launch_bounds__(256) void head1_kernel(const float* __restrict__ lnp,
                                                    const float* __restrict__ w,
                                                    const float* __restrict__ bb,
                                                    float* __restrict__ hid) {
  int idx = blockIdx.x * 256 + threadIdx.x;
  int b = idx >> 10, n = idx & 1023;
  const float* xr = lnp + (size_t)b * DM;
  const float* wr = w + (size_t)n * DM;
  float s = 0.f;
  for (int k = 0; k < DM; k += 4) {
    float4 xv = *(const float4*)(xr + k);
    float4 wv = *(const float4*)(wr + k);
    s += xv.x * wv.x + xv.y * wv.y + xv.z * wv.z + xv.w * wv.w;
  }
  hid[idx] = gelu_f(s + bb[n]);
}

__global__ __launch_bounds__(128) void head2_kernel(const float* __restrict__ hid,
                                                    const float* __restrict__ w,
                                                    const float* __restrict__ bb,
                                                    float* __restrict__ dout) {
  int t = threadIdx.x;
  if (t < BN_ * NC) {
    int b = t / NC, n = t - b * NC;
    const float* xr = hid + (size_t)b * MLPD;
    const float* wr = w + (size_t)n * MLPD;
    float s = 0.f;
    for (int k = 0; k < MLPD; k += 4) {
      float4 xv = *(const float4*)(xr + k);
      float4 wv = *(const float4*)(wr + k);
      s += xv.x * wv.x + xv.y * wv.y + xv.z * wv.z + xv.w * wv.w;
    }
    dout[OUT_LOGITS + t] = s + bb[n];
  }
}

// ---------------- launch ----------------
extern "C" void kernel_launch(void* const* d_in, const int* in_sizes, int n_in,
                              void* d_out, int out_size, void* d_ws, size_t ws_size,
                              hipStream_t stream) {
  (void)in_sizes; (void)n_in; (void)out_size; (void)ws_size;
  const float* xyzs     = (const float*)d_in[0];
  const float* oldf     = (const float*)d_in[1];
  const float* conv_d_w = (const float*)d_in[2];
  const float* conv_f_w = (const float*)d_in[3];
  const float* pos_w    = (const float*)d_in[4];
  const float* pos_b    = (const float*)d_in[5];
  const float* contr_w  = (const float*)d_in[6];
  const float* contr_b  = (const float*)d_in[7];
  const float* ln1_s    = (const float*)d_in[8];
  const float* ln1_b    = (const float*)d_in[9];
  const float* qkv_w    = (const float*)d_in[10];
  const float* out_w    = (const float*)d_in[11];
  const float* out_b    = (const float*)d_in[12];
  const float* ln2_s    = (const float*)d_in[13];
  const float* ln2_b    = (const float*)d_in[14];
  const float* ff1_w    = (const float*)d_in[15];
  const float* ff1_b    = (const float*)d_in[16];
  const float* ff2_w    = (const float*)d_in[17];
  const float* ff2_b    = (const float*)d_in[18];
  const float* hl_s     = (const float*)d_in[19];
  const float* hl_b     = (const float*)d_in[20];
  const float* h1_w     = (const float*)d_in[21];
  const float* h1_b     = (const float*)d_in[22];
  const float* h2_w     = (const float*)d_in[23];
  const float* h2_b     = (const float*)d_in[24];
  float* dout = (float*)d_out;
  char* base = (char*)d_ws;

  float* anchor = (float*)base;            base += (size_t)BN_ * TO * MM * 3 * 4;   // 73728
  float* x      = (float*)base;            base += (size_t)BL * DM * 4;             // 12.58MB
  short* qkvh   = (short*)base;            base += (size_t)BL * 3 * DM * 2;         // 18.87MB
  short* qkvl   = (short*)base;            base += (size_t)BL * 3 * DM * 2;
  short* atnh   = (short*)base;            base += (size_t)BL * DM * 2;             // 6.29MB
  short* atnl   = (short*)base;            base += (size_t)BL * DM * 2;
  short* hh     = (short*)base;            base += (size_t)BL * DM * 2;
  short* hl     = (short*)base;            base += (size_t)BL * DM * 2;
  float* partial= (float*)base;            base += (size_t)BN_ * TO * DM * 4;
  float* pooled = (float*)base;            base += (size_t)BN_ * DM * 4;
  float* lnp    = (float*)base;            base += (size_t)BN_ * DM * 4;
  float* hid    = (float*)base;            base += (size_t)BN_ * MLPD * 4;
  short* fh = qkvh;  // FF hidden aliases qkv (consumed by then)
  short* fl = qkvl;

  fps_kernel<<<BN_ * TO, 256, 0, stream>>>(xyzs, anchor);
  ballconv_kernel<<<BN_ * TO * MM, 64, 0, stream>>>(xyzs, oldf, anchor, conv_d_w, conv_f_w, dout);
  posx_kernel<<<(BL * DM) / 256, 256, 0, stream>>>(anchor, pos_w, pos_b, contr_w, contr_b, dout, x);

  for (int l = 0; l < 4; ++l) {
    ln_split_kernel<<<BL, 64, 0, stream>>>(x, ln1_s + l * DM, ln1_b + l * DM, hh, hl);
    mgemm_kernel<1><<<dim3(3 * DM / 128, BL / 128), 256, 0, stream>>>(
        hh, hl, qkv_w + (size_t)l * 3 * DM * DM, nullptr, nullptr,
        nullptr, qkvh, qkvl, BL, 3 * DM, DM);
    mattn_kernel<<<dim3(LL / 64, BN_ * NH), 256, 0, stream>>>(qkvh, qkvl, atnh, atnl);
    mgemm_kernel<3><<<dim3(DM / 128, BL / 128), 256, 0, stream>>>(
        atnh, atnl, out_w + (size_t)l * DM * DM, out_b + l * DM, x,
        x, nullptr, nullptr, BL, DM, DM);
    ln_split_kernel<<<BL, 64, 0, stream>>>(x, ln2_s + l * DM, ln2_b + l * DM, hh, hl);
    mgemm_kernel<2><<<dim3(MLPD / 128, BL / 128), 256, 0, stream>>>(
        hh, hl, ff1_w + (size_t)l * MLPD * DM, ff1_b + l * MLPD, nullptr,
        nullptr, fh, fl, BL, MLPD, DM);
    mgemm_kernel<3><<<dim3(DM / 128, BL / 128), 256, 0, stream>>>(
        fh, fl, ff2_w + (size_t)l * DM * MLPD, ff2_b + l * DM, x,
        x, nullptr, nullptr, BL, DM, MLPD);
  }

  poolmax1_kernel<<<dim3(TO, BN_), 256, 0, stream>>>(x, partial);
  poolmax2_kernel<<<(BN_ * DM) / 256, 256, 0, stream>>>(partial, pooled);
  ln_kernel<<<BN_, 64, 0, stream>>>(pooled, hl_s, hl_b, lnp);
  head1_kernel<<<(BN_ * MLPD) / 256, 256, 0, stream>>>(lnp, h1_w, h1_b, hid);
  head2_kernel<<<1, 128, 0, stream>>>(hid, h2_w, h2_b, dout);
}